// Round 6
// baseline (178.212 us; speedup 1.0000x reference)
//
#include <hip/hip_runtime.h>
#include <hip/hip_bf16.h>

#define DEVI __device__ __forceinline__

typedef __attribute__((ext_vector_type(8))) short bf16x8;
typedef __attribute__((ext_vector_type(4))) short bf16x4;
typedef __attribute__((ext_vector_type(4))) float f32x4;

DEVI unsigned short f2bf(float f) {
    unsigned u = __float_as_uint(f);
    u += 0x7FFF + ((u >> 16) & 1);
    return (unsigned short)(u >> 16);
}
DEVI float bf2f(unsigned short h) {
    return __uint_as_float(((unsigned)h) << 16);
}
DEVI f32x4 mfma16(bf16x8 a, bf16x8 b, f32x4 c) {
    return __builtin_amdgcn_mfma_f32_16x16x32_bf16(a, b, c, 0, 0, 0);
}
DEVI void gload_lds16(const void* g, void* l) {
    __builtin_amdgcn_global_load_lds(
        (const __attribute__((address_space(1))) unsigned int*)g,
        (__attribute__((address_space(3))) unsigned int*)l, 16, 0, 0);
}

// ---------------------------------------------------------------------------
// Prep: X f32 [4096*1024] -> bf16
// ---------------------------------------------------------------------------
__global__ __launch_bounds__(256) void k_cvt(
    const float* __restrict__ X, unsigned short* __restrict__ Xb)
{
    int i = blockIdx.x * 256 + threadIdx.x;
#pragma unroll
    for (int j = 0; j < 4; ++j) {
        int idx = i + j * 262144;
        float4 v = *(const float4*)(X + (size_t)idx * 4);
        bf16x4 hv;
        hv[0] = (short)f2bf(v.x); hv[1] = (short)f2bf(v.y);
        hv[2] = (short)f2bf(v.z); hv[3] = (short)f2bf(v.w);
        *(bf16x4*)(Xb + (size_t)idx * 4) = hv;
    }
}

// ---------------------------------------------------------------------------
// Prep: W f32 [1024][N] -> Wt bf16 [N][1024]  (transpose + convert)
// ---------------------------------------------------------------------------
__global__ __launch_bounds__(256) void k_wt(
    const float* __restrict__ W, unsigned short* __restrict__ Wt, int N)
{
    __shared__ unsigned short T[64][72];   // [n][k]
    const int tid = threadIdx.x;
    const int n0 = blockIdx.x * 64, k0 = blockIdx.y * 64;
#pragma unroll
    for (int j = 0; j < 4; ++j) {
        int idx = tid + j * 256;
        int kk = idx >> 4, c4 = (idx & 15) << 2;
        float4 v = *(const float4*)(W + (size_t)(k0 + kk) * N + n0 + c4);
        T[c4 + 0][kk] = f2bf(v.x); T[c4 + 1][kk] = f2bf(v.y);
        T[c4 + 2][kk] = f2bf(v.z); T[c4 + 3][kk] = f2bf(v.w);
    }
    __syncthreads();
#pragma unroll
    for (int j = 0; j < 4; ++j) {
        int idx = tid + j * 256;
        int n = idx >> 4, c4 = (idx & 15) << 2;
        *(bf16x4*)(Wt + (size_t)(n0 + n) * 1024 + k0 + c4) = *(bf16x4*)&T[n][c4];
    }
}

// ---------------------------------------------------------------------------
// GEMM1: qkv[4096][3072] bf16 = Xb[4096][1024] @ Wt1^T   (B^T layout, m97-style)
// ---------------------------------------------------------------------------
__global__ __launch_bounds__(256) void k_gemm1(
    const unsigned short* __restrict__ A, const unsigned short* __restrict__ B,
    unsigned short* __restrict__ C)
{
    __shared__ unsigned short As[128 * 64];
    __shared__ unsigned short Bs[128 * 64];
    const int tid = threadIdx.x, lane = tid & 63, wid = tid >> 6;
    const int wr = (wid >> 1) * 64, wc = (wid & 1) * 64;
    const int row0 = blockIdx.y * 128, col0 = blockIdx.x * 128;
    const int rsel = lane & 15, kgr = (lane >> 4) * 8;
    const int lr = lane >> 3, lc = (lane & 7) * 8;

    f32x4 acc[4][4];
#pragma unroll
    for (int i = 0; i < 4; ++i)
#pragma unroll
        for (int j = 0; j < 4; ++j) acc[i][j] = (f32x4){0.f, 0.f, 0.f, 0.f};

    for (int k0 = 0; k0 < 1024; k0 += 64) {
        __syncthreads();
#pragma unroll
        for (int i = 0; i < 4; ++i) {
            int rb = wid * 32 + i * 8;
            gload_lds16(A + (size_t)(row0 + rb + lr) * 1024 + k0 + lc, As + rb * 64);
            gload_lds16(B + (size_t)(col0 + rb + lr) * 1024 + k0 + lc, Bs + rb * 64);
        }
        __syncthreads();
#pragma unroll
        for (int ks = 0; ks < 2; ++ks) {
            bf16x8 a[4], b[4];
            int ko = ks * 32 + kgr;
#pragma unroll
            for (int mi = 0; mi < 4; ++mi)
                a[mi] = *(const bf16x8*)(As + (wr + mi * 16 + rsel) * 64 + ko);
#pragma unroll
            for (int nj = 0; nj < 4; ++nj)
                b[nj] = *(const bf16x8*)(Bs + (wc + nj * 16 + rsel) * 64 + ko);
#pragma unroll
            for (int mi = 0; mi < 4; ++mi)
#pragma unroll
                for (int nj = 0; nj < 4; ++nj)
                    acc[mi][nj] = mfma16(a[mi], b[nj], acc[mi][nj]);
        }
    }
    const int rbase = row0 + wr + ((lane >> 4) << 2);
    const int cbase = col0 + wc + rsel;
#pragma unroll
    for (int mi = 0; mi < 4; ++mi)
#pragma unroll
        for (int nj = 0; nj < 4; ++nj)
#pragma unroll
            for (int r = 0; r < 4; ++r)
                C[(size_t)(rbase + mi * 16 + r) * 3072 + cbase + nj * 16] =
                    f2bf(acc[mi][nj][r]);
}

// ---------------------------------------------------------------------------
// Build Vt[bh][64][2048] from qkv V-section via LDS transpose
// ---------------------------------------------------------------------------
__global__ __launch_bounds__(256) void k_vt(
    const unsigned short* __restrict__ qkv, unsigned short* __restrict__ Vt)
{
    __shared__ unsigned short T[64][72];   // [n][dv]
    const int tid = threadIdx.x, lane = tid & 63, wid = tid >> 6;
    const int bh = blockIdx.y, b = bh >> 4, h = bh & 15;
    const int n0 = blockIdx.x * 64;
    const unsigned short* src = qkv + (size_t)(b * 2048 + n0) * 3072 + 2048 + h * 64;
#pragma unroll
    for (int j = 0; j < 2; ++j) {
        int idx = tid + j * 256;
        int n = idx >> 3, c8 = (idx & 7) << 3;
        *(bf16x8*)&T[n][c8] = *(const bf16x8*)(src + (size_t)n * 3072 + c8);
    }
    __syncthreads();
#pragma unroll
    for (int i = 0; i < 16; ++i) {
        int dv = wid * 16 + i;
        Vt[((size_t)bh * 64 + dv) * 2048 + n0 + lane] = T[lane][dv];
    }
}

// ---------------------------------------------------------------------------
// vsum[bh*64+dv] = sum_n V[bh][n][dv]   (read Vt rows, contiguous)
// ---------------------------------------------------------------------------
__global__ __launch_bounds__(256) void k_vsum(
    const unsigned short* __restrict__ Vt, float* __restrict__ vsum)
{
    int wid = threadIdx.x >> 6, lane = threadIdx.x & 63;
    int row = blockIdx.x * 4 + wid;            // 0..2047
    float s = 0.f;
#pragma unroll
    for (int it = 0; it < 4; ++it) {
        bf16x8 v = *(const bf16x8*)(Vt + (size_t)row * 2048 + it * 512 + lane * 8);
#pragma unroll
        for (int i = 0; i < 8; ++i) s += bf2f((unsigned short)v[i]);
    }
#pragma unroll
    for (int m = 32; m; m >>= 1) s += __shfl_xor(s, m);
    if (lane == 0) vsum[row] = s;
}

// ---------------------------------------------------------------------------
// Flash attention, q-tile 128 (32 q-rows/wave, nq=2), grid 512, XCD-swizzled.
// No online softmax (P = exp2(s), fixed shift 0 — exact after final divide).
// nq=2 amortizes K/V fragment LDS reads over 2x MFMAs (24 reads / 36 MFMA
// per wave-kt vs 20/18 at nq=1): LDS-read bytes per FLOP drop 40%.
// ---------------------------------------------------------------------------
__global__ __launch_bounds__(256) void k_attn(
    const unsigned short* __restrict__ qkv, const unsigned short* __restrict__ Vt,
    const float* __restrict__ vsum,
    const float* __restrict__ alpha_p, const float* __restrict__ beta_p,
    const float* __restrict__ gamma_p,
    unsigned short* __restrict__ AO)
{
    __shared__ unsigned short Qs[128][72];
    __shared__ unsigned short Ks[64][72];
    __shared__ unsigned short Vs[64][72];     // [dv][key]
    __shared__ unsigned short Ps[4][32][72];  // per-wave P tile [qrow][key]
    const int tid = threadIdx.x, lane = tid & 63, wid = tid >> 6;
    // bijective XCD swizzle: nwg=512, 64 consecutive logical blocks per XCD
    const int swz = (blockIdx.x & 7) * 64 + (blockIdx.x >> 3);
    const int bh = swz >> 4, qtb = swz & 15;
    const int b = bh >> 4, h = bh & 15;
    const int q0 = qtb * 128;
    const int rsel = lane & 15, kgr = (lane >> 4) * 8;
    const int g4 = (lane >> 4) << 2;
    const int wq0 = wid * 32;

    // stage Q, pre-scaled by log2(e)/32 so scores are in exp2 domain
    const float QSC = 1.4426950408889634f / 32.0f;
    const unsigned short* Qg = qkv + (size_t)(b * 2048 + q0) * 3072 + h * 64;
#pragma unroll
    for (int j = 0; j < 4; ++j) {
        int idx = tid + j * 256; int r = idx >> 3, c8 = (idx & 7) << 3;
        bf16x8 qv = *(const bf16x8*)(Qg + (size_t)r * 3072 + c8);
        bf16x8 qs;
#pragma unroll
        for (int e = 0; e < 8; ++e)
            qs[e] = (short)f2bf(bf2f((unsigned short)qv[e]) * QSC);
        *(bf16x8*)(&Qs[r][c8]) = qs;
    }

    f32x4 o[2][4], ol[2];
#pragma unroll
    for (int qt = 0; qt < 2; ++qt) {
#pragma unroll
        for (int dj = 0; dj < 4; ++dj) o[qt][dj] = (f32x4){0.f, 0.f, 0.f, 0.f};
        ol[qt] = (f32x4){0.f, 0.f, 0.f, 0.f};
    }

    bf16x8 ones;
#pragma unroll
    for (int e = 0; e < 8; ++e) ones[e] = (short)0x3F80;   // bf16 1.0

    const unsigned short* Kg = qkv + (size_t)(b * 2048) * 3072 + 1024 + h * 64;

    for (int kt = 0; kt < 32; ++kt) {
        int k0 = kt * 64;
        __syncthreads();
#pragma unroll
        for (int j = 0; j < 2; ++j) {
            int idx = tid + j * 256; int r = idx >> 3, c8 = (idx & 7) << 3;
            *(bf16x8*)(&Ks[r][c8]) = *(const bf16x8*)(Kg + (size_t)(k0 + r) * 3072 + c8);
            *(bf16x8*)(&Vs[r][c8]) = *(const bf16x8*)(Vt + ((size_t)bh * 64 + r) * 2048 + k0 + c8);
        }
        __syncthreads();

        // QK^T swapped: s[qt][kj] = S^T tile [k=kj*16+g4+r][q=wq0+qt*16+rsel]
        f32x4 s[2][4];
#pragma unroll
        for (int qt = 0; qt < 2; ++qt)
#pragma unroll
            for (int kj = 0; kj < 4; ++kj) s[qt][kj] = (f32x4){0.f, 0.f, 0.f, 0.f};
#pragma unroll
        for (int ks = 0; ks < 2; ++ks) {
            bf16x8 ak[4], bq[2];
            int ko = ks * 32 + kgr;
#pragma unroll
            for (int kj = 0; kj < 4; ++kj)
                ak[kj] = *(bf16x8*)(&Ks[kj * 16 + rsel][ko]);
#pragma unroll
            for (int qt = 0; qt < 2; ++qt)
                bq[qt] = *(bf16x8*)(&Qs[wq0 + qt * 16 + rsel][ko]);
#pragma unroll
            for (int qt = 0; qt < 2; ++qt)
#pragma unroll
                for (int kj = 0; kj < 4; ++kj)
                    s[qt][kj] = mfma16(ak[kj], bq[qt], s[qt][kj]);
        }

        // P = exp2(s), packed bf16 write (no max subtraction needed)
#pragma unroll
        for (int qt = 0; qt < 2; ++qt)
#pragma unroll
            for (int kj = 0; kj < 4; ++kj) {
                float p0 = exp2f(s[qt][kj][0]);
                float p1 = exp2f(s[qt][kj][1]);
                float p2 = exp2f(s[qt][kj][2]);
                float p3 = exp2f(s[qt][kj][3]);
                union { __hip_bfloat162 h2[2]; uint2 u; } pk;
                pk.h2[0] = __float22bfloat162_rn(make_float2(p0, p1));
                pk.h2[1] = __float22bfloat162_rn(make_float2(p2, p3));
                *(uint2*)(&Ps[wid][qt * 16 + rsel][kj * 16 + g4]) = pk.u;
            }

        // PV + row-sum via ones (same-wave LDS dep; compiler inserts lgkmcnt)
#pragma unroll
        for (int ks = 0; ks < 2; ++ks) {
            bf16x8 pa[2], vb[4];
            int ko = ks * 32 + kgr;
#pragma unroll
            for (int qt = 0; qt < 2; ++qt)
                pa[qt] = *(bf16x8*)(&Ps[wid][qt * 16 + rsel][ko]);
#pragma unroll
            for (int dj = 0; dj < 4; ++dj)
                vb[dj] = *(bf16x8*)(&Vs[dj * 16 + rsel][ko]);
#pragma unroll
            for (int qt = 0; qt < 2; ++qt) {
#pragma unroll
                for (int dj = 0; dj < 4; ++dj)
                    o[qt][dj] = mfma16(pa[qt], vb[dj], o[qt][dj]);
                ol[qt] = mfma16(pa[qt], ones, ol[qt]);   // l in ol[qt][r]
            }
        }
    }

    // epilogue: beta*softmax + alpha*V[q] - gamma/n * vsum
    const float alpha = *alpha_p, beta = *beta_p;
    const float gn = (*gamma_p) / 2048.0f;
#pragma unroll
    for (int qt = 0; qt < 2; ++qt) {
        float linv[4];
#pragma unroll
        for (int r = 0; r < 4; ++r)
            linv[r] = beta / ol[qt][r];
#pragma unroll
        for (int dj = 0; dj < 4; ++dj)
#pragma unroll
            for (int r = 0; r < 4; ++r) {
                int qrow = q0 + wq0 + qt * 16 + g4 + r;
                int dv = dj * 16 + rsel;
                float ov = o[qt][dj][r] * linv[r];
                float vdiag = bf2f(qkv[(size_t)(b * 2048 + qrow) * 3072 + 2048 + h * 64 + dv]);
                float vs = vsum[bh * 64 + dv];
                float res = ov + alpha * vdiag - gn * vs;
                AO[(size_t)(b * 2048 + qrow) * 1024 + h * 64 + dv] = f2bf(res);
            }
    }
}

// ---------------------------------------------------------------------------
// GEMM2: out f32[4096][1024] = AO bf16 @ Wt2^T + bias
// ---------------------------------------------------------------------------
__global__ __launch_bounds__(256) void k_gemm2(
    const unsigned short* __restrict__ A, const unsigned short* __restrict__ B,
    const float* __restrict__ bias, float* __restrict__ Out)
{
    __shared__ unsigned short As[128 * 64];
    __shared__ unsigned short Bs[128 * 64];
    const int tid = threadIdx.x, lane = tid & 63, wid = tid >> 6;
    const int wr = (wid >> 1) * 64, wc = (wid & 1) * 64;
    const int row0 = blockIdx.y * 128, col0 = blockIdx.x * 128;
    const int rsel = lane & 15, kgr = (lane >> 4) * 8;
    const int lr = lane >> 3, lc = (lane & 7) * 8;

    f32x4 acc[4][4];
#pragma unroll
    for (int i = 0; i < 4; ++i)
#pragma unroll
        for (int j = 0; j < 4; ++j) acc[i][j] = (f32x4){0.f, 0.f, 0.f, 0.f};

    for (int k0 = 0; k0 < 1024; k0 += 64) {
        __syncthreads();
#pragma unroll
        for (int i = 0; i < 4; ++i) {
            int rb = wid * 32 + i * 8;
            gload_lds16(A + (size_t)(row0 + rb + lr) * 1024 + k0 + lc, As + rb * 64);
            gload_lds16(B + (size_t)(col0 + rb + lr) * 1024 + k0 + lc, Bs + rb * 64);
        }
        __syncthreads();
#pragma unroll
        for (int ks = 0; ks < 2; ++ks) {
            bf16x8 a[4], b[4];
            int ko = ks * 32 + kgr;
#pragma unroll
            for (int mi = 0; mi < 4; ++mi)
                a[mi] = *(const bf16x8*)(As + (wr + mi * 16 + rsel) * 64 + ko);
#pragma unroll
            for (int nj = 0; nj < 4; ++nj)
                b[nj] = *(const bf16x8*)(Bs + (wc + nj * 16 + rsel) * 64 + ko);
#pragma unroll
            for (int mi = 0; mi < 4; ++mi)
#pragma unroll
                for (int nj = 0; nj < 4; ++nj)
                    acc[mi][nj] = mfma16(a[mi], b[nj], acc[mi][nj]);
        }
    }
    const int rbase = row0 + wr + ((lane >> 4) << 2);
    const int cbase = col0 + wc + rsel;
#pragma unroll
    for (int mi = 0; mi < 4; ++mi)
#pragma unroll
        for (int nj = 0; nj < 4; ++nj) {
            int gc = cbase + nj * 16;
            float bv = bias[gc];
#pragma unroll
            for (int r = 0; r < 4; ++r)
                Out[(size_t)(rbase + mi * 16 + r) * 1024 + gc] = acc[mi][nj][r] + bv;
        }
}

// ---------------------------------------------------------------------------
extern "C" void kernel_launch(void* const* d_in, const int* in_sizes, int n_in,
                              void* d_out, int out_size, void* d_ws, size_t ws_size,
                              hipStream_t stream) {
    const float* x     = (const float*)d_in[0];
    const float* Wqkv  = (const float*)d_in[1];
    const float* Wout  = (const float*)d_in[2];
    const float* bout  = (const float*)d_in[3];
    const float* alpha = (const float*)d_in[4];
    const float* beta  = (const float*)d_in[5];
    const float* gamma = (const float*)d_in[6];
    float* out = (float*)d_out;

    char* ws = (char*)d_ws;
    unsigned short* Xb  = (unsigned short*)(ws);               // 8 MB (reused as AO)
    unsigned short* Wt1 = (unsigned short*)(ws + 8388608);     // 6 MB
    unsigned short* Wt2 = (unsigned short*)(ws + 14680064);    // 2 MB
    unsigned short* qkv = (unsigned short*)(ws + 16777216);    // 24 MB
    unsigned short* Vt  = (unsigned short*)(ws + 41943040);    // 8 MB
    float* vsum         = (float*)(ws + 50331648);             // 8 KB
    unsigned short* AO  = Xb;   // Xb dead after k_gemm1

    k_cvt<<<1024, 256, 0, stream>>>(x, Xb);
    k_wt<<<dim3(48, 16), 256, 0, stream>>>(Wqkv, Wt1, 3072);
    k_wt<<<dim3(16, 16), 256, 0, stream>>>(Wout, Wt2, 1024);
    k_gemm1<<<dim3(24, 32), 256, 0, stream>>>(Xb, Wt1, qkv);
    k_vt<<<dim3(32, 32), 256, 0, stream>>>(qkv, Vt);
    k_vsum<<<512, 256, 0, stream>>>(Vt, vsum);
    k_attn<<<512, 256, 0, stream>>>(qkv, Vt, vsum, alpha, beta, gamma, AO);
    k_gemm2<<<dim3(8, 32), 256, 0, stream>>>(AO, Wt2, bout, out);
}

// Round 7
// 169.377 us; speedup vs baseline: 1.0522x; 1.0522x over previous
//
#include <hip/hip_runtime.h>
#include <hip/hip_bf16.h>

#define DEVI __device__ __forceinline__

typedef __attribute__((ext_vector_type(8))) short bf16x8;
typedef __attribute__((ext_vector_type(4))) short bf16x4;
typedef __attribute__((ext_vector_type(4))) float f32x4;

DEVI unsigned short f2bf(float f) {
    unsigned u = __float_as_uint(f);
    u += 0x7FFF + ((u >> 16) & 1);
    return (unsigned short)(u >> 16);
}
DEVI float bf2f(unsigned short h) {
    return __uint_as_float(((unsigned)h) << 16);
}
DEVI f32x4 mfma16(bf16x8 a, bf16x8 b, f32x4 c) {
    return __builtin_amdgcn_mfma_f32_16x16x32_bf16(a, b, c, 0, 0, 0);
}
DEVI void gload_lds16(const void* g, void* l) {
    __builtin_amdgcn_global_load_lds(
        (const __attribute__((address_space(1))) unsigned int*)g,
        (__attribute__((address_space(3))) unsigned int*)l, 16, 0, 0);
}

// ---------------------------------------------------------------------------
// Prep: X f32 [4096*1024] -> bf16
// ---------------------------------------------------------------------------
__global__ __launch_bounds__(256) void k_cvt(
    const float* __restrict__ X, unsigned short* __restrict__ Xb)
{
    int i = blockIdx.x * 256 + threadIdx.x;
#pragma unroll
    for (int j = 0; j < 4; ++j) {
        int idx = i + j * 262144;
        float4 v = *(const float4*)(X + (size_t)idx * 4);
        bf16x4 hv;
        hv[0] = (short)f2bf(v.x); hv[1] = (short)f2bf(v.y);
        hv[2] = (short)f2bf(v.z); hv[3] = (short)f2bf(v.w);
        *(bf16x4*)(Xb + (size_t)idx * 4) = hv;
    }
}

// ---------------------------------------------------------------------------
// Prep: W f32 [1024][N] -> Wt bf16 [N][1024]  (transpose + convert)
// ---------------------------------------------------------------------------
__global__ __launch_bounds__(256) void k_wt(
    const float* __restrict__ W, unsigned short* __restrict__ Wt, int N)
{
    __shared__ unsigned short T[64][72];   // [n][k]
    const int tid = threadIdx.x;
    const int n0 = blockIdx.x * 64, k0 = blockIdx.y * 64;
#pragma unroll
    for (int j = 0; j < 4; ++j) {
        int idx = tid + j * 256;
        int kk = idx >> 4, c4 = (idx & 15) << 2;
        float4 v = *(const float4*)(W + (size_t)(k0 + kk) * N + n0 + c4);
        T[c4 + 0][kk] = f2bf(v.x); T[c4 + 1][kk] = f2bf(v.y);
        T[c4 + 2][kk] = f2bf(v.z); T[c4 + 3][kk] = f2bf(v.w);
    }
    __syncthreads();
#pragma unroll
    for (int j = 0; j < 4; ++j) {
        int idx = tid + j * 256;
        int n = idx >> 4, c4 = (idx & 15) << 2;
        *(bf16x4*)(Wt + (size_t)(n0 + n) * 1024 + k0 + c4) = *(bf16x4*)&T[n][c4];
    }
}

// ---------------------------------------------------------------------------
// GEMM1: qkv[4096][3072] bf16 = Xb[4096][1024] @ Wt1^T   (B^T layout, m97-style)
// ---------------------------------------------------------------------------
__global__ __launch_bounds__(256) void k_gemm1(
    const unsigned short* __restrict__ A, const unsigned short* __restrict__ B,
    unsigned short* __restrict__ C)
{
    __shared__ unsigned short As[128 * 64];
    __shared__ unsigned short Bs[128 * 64];
    const int tid = threadIdx.x, lane = tid & 63, wid = tid >> 6;
    const int wr = (wid >> 1) * 64, wc = (wid & 1) * 64;
    const int row0 = blockIdx.y * 128, col0 = blockIdx.x * 128;
    const int rsel = lane & 15, kgr = (lane >> 4) * 8;
    const int lr = lane >> 3, lc = (lane & 7) * 8;

    f32x4 acc[4][4];
#pragma unroll
    for (int i = 0; i < 4; ++i)
#pragma unroll
        for (int j = 0; j < 4; ++j) acc[i][j] = (f32x4){0.f, 0.f, 0.f, 0.f};

    for (int k0 = 0; k0 < 1024; k0 += 64) {
        __syncthreads();
#pragma unroll
        for (int i = 0; i < 4; ++i) {
            int rb = wid * 32 + i * 8;
            gload_lds16(A + (size_t)(row0 + rb + lr) * 1024 + k0 + lc, As + rb * 64);
            gload_lds16(B + (size_t)(col0 + rb + lr) * 1024 + k0 + lc, Bs + rb * 64);
        }
        __syncthreads();
#pragma unroll
        for (int ks = 0; ks < 2; ++ks) {
            bf16x8 a[4], b[4];
            int ko = ks * 32 + kgr;
#pragma unroll
            for (int mi = 0; mi < 4; ++mi)
                a[mi] = *(const bf16x8*)(As + (wr + mi * 16 + rsel) * 64 + ko);
#pragma unroll
            for (int nj = 0; nj < 4; ++nj)
                b[nj] = *(const bf16x8*)(Bs + (wc + nj * 16 + rsel) * 64 + ko);
#pragma unroll
            for (int mi = 0; mi < 4; ++mi)
#pragma unroll
                for (int nj = 0; nj < 4; ++nj)
                    acc[mi][nj] = mfma16(a[mi], b[nj], acc[mi][nj]);
        }
    }
    const int rbase = row0 + wr + ((lane >> 4) << 2);
    const int cbase = col0 + wc + rsel;
#pragma unroll
    for (int mi = 0; mi < 4; ++mi)
#pragma unroll
        for (int nj = 0; nj < 4; ++nj)
#pragma unroll
            for (int r = 0; r < 4; ++r)
                C[(size_t)(rbase + mi * 16 + r) * 3072 + cbase + nj * 16] =
                    f2bf(acc[mi][nj][r]);
}

// ---------------------------------------------------------------------------
// Build Vt[bh][64][2048] from qkv V-section via LDS transpose
// ---------------------------------------------------------------------------
__global__ __launch_bounds__(256) void k_vt(
    const unsigned short* __restrict__ qkv, unsigned short* __restrict__ Vt)
{
    __shared__ unsigned short T[64][72];   // [n][dv]
    const int tid = threadIdx.x, lane = tid & 63, wid = tid >> 6;
    const int bh = blockIdx.y, b = bh >> 4, h = bh & 15;
    const int n0 = blockIdx.x * 64;
    const unsigned short* src = qkv + (size_t)(b * 2048 + n0) * 3072 + 2048 + h * 64;
#pragma unroll
    for (int j = 0; j < 2; ++j) {
        int idx = tid + j * 256;
        int n = idx >> 3, c8 = (idx & 7) << 3;
        *(bf16x8*)&T[n][c8] = *(const bf16x8*)(src + (size_t)n * 3072 + c8);
    }
    __syncthreads();
#pragma unroll
    for (int i = 0; i < 16; ++i) {
        int dv = wid * 16 + i;
        Vt[((size_t)bh * 64 + dv) * 2048 + n0 + lane] = T[lane][dv];
    }
}

// ---------------------------------------------------------------------------
// vsum[bh*64+dv] = sum_n V[bh][n][dv]   (read Vt rows, contiguous)
// ---------------------------------------------------------------------------
__global__ __launch_bounds__(256) void k_vsum(
    const unsigned short* __restrict__ Vt, float* __restrict__ vsum)
{
    int wid = threadIdx.x >> 6, lane = threadIdx.x & 63;
    int row = blockIdx.x * 4 + wid;            // 0..2047
    float s = 0.f;
#pragma unroll
    for (int it = 0; it < 4; ++it) {
        bf16x8 v = *(const bf16x8*)(Vt + (size_t)row * 2048 + it * 512 + lane * 8);
#pragma unroll
        for (int i = 0; i < 8; ++i) s += bf2f((unsigned short)v[i]);
    }
#pragma unroll
    for (int m = 32; m; m >>= 1) s += __shfl_xor(s, m);
    if (lane == 0) vsum[row] = s;
}

// ---------------------------------------------------------------------------
// Flash attention, q-tile 64, grid 1024, XCD-swizzled. exp2-only softmax.
// T3: double-buffered gload_lds K/V staging, prefetch issued before compute,
//     one vmcnt(0)+barrier per tile (load latency hides under compute).
// T2: linear LDS + XOR swizzle (source-side for gload_lds; same involution on
//     reads) -> all LDS accesses <=2-way (free).  Q held in registers.
// T5: setprio around MFMA clusters.
// ---------------------------------------------------------------------------
__global__ __launch_bounds__(256) void k_attn(
    const unsigned short* __restrict__ qkv, const unsigned short* __restrict__ Vt,
    const float* __restrict__ vsum,
    const float* __restrict__ alpha_p, const float* __restrict__ beta_p,
    const float* __restrict__ gamma_p,
    unsigned short* __restrict__ AO)
{
    __shared__ unsigned short Ks[2][64][64];   // linear, swizzled content
    __shared__ unsigned short Vs[2][64][64];   // linear, swizzled content
    __shared__ unsigned short Ps[4][16][64];   // per-wave, 16B-slot XOR swizzle
    const int tid = threadIdx.x, lane = tid & 63, wid = tid >> 6;
    // bijective XCD swizzle: nwg=1024, 128 consecutive logical blocks per XCD
    const int swz = (blockIdx.x & 7) * 128 + (blockIdx.x >> 3);
    const int bh = swz >> 5, qtb = swz & 31;
    const int b = bh >> 4, h = bh & 15;
    const int q0 = qtb * 64;
    const int rsel = lane & 15, g = lane >> 4;
    const int g4 = g << 2;
    const int wq0 = wid * 16;
    const int r7 = rsel & 7;

    // Q fragments in registers, pre-scaled by log2(e)/32 (exp2 domain)
    const float QSC = 1.4426950408889634f / 32.0f;
    bf16x8 bq[2];
    {
        const unsigned short* qrow =
            qkv + (size_t)(b * 2048 + q0 + wq0 + rsel) * 3072 + h * 64;
#pragma unroll
        for (int ks = 0; ks < 2; ++ks) {
            bf16x8 qv = *(const bf16x8*)(qrow + ks * 32 + g * 8);
#pragma unroll
            for (int e = 0; e < 8; ++e)
                bq[ks][e] = (short)f2bf(bf2f((unsigned short)qv[e]) * QSC);
        }
    }

    // staging source mapping (inverse-swizzled so LDS reads can XOR)
    const int srow = lane >> 3;                 // 0..7 within 8-row slab
    const int sslot = (lane & 7) ^ srow;        // 16B slot in global row
    const unsigned short* Kg = qkv + (size_t)(b * 2048) * 3072 + 1024 + h * 64;
    const unsigned short* Vg = Vt + (size_t)bh * 64 * 2048;

#define STAGE(KT, BUF)                                                         \
    {                                                                          \
        int _k0 = (KT) * 64;                                                   \
        _Pragma("unroll")                                                      \
        for (int j = 0; j < 2; ++j) {                                          \
            int rb = wid * 16 + j * 8;                                         \
            gload_lds16(Kg + (size_t)(_k0 + rb + srow) * 3072 + sslot * 8,     \
                        &Ks[BUF][rb][0]);                                      \
            gload_lds16(Vg + (size_t)(rb + srow) * 2048 + _k0 + sslot * 8,     \
                        &Vs[BUF][rb][0]);                                      \
        }                                                                      \
    }

    f32x4 o[4], ol;
#pragma unroll
    for (int dj = 0; dj < 4; ++dj) o[dj] = (f32x4){0.f, 0.f, 0.f, 0.f};
    ol = (f32x4){0.f, 0.f, 0.f, 0.f};
    bf16x8 ones;
#pragma unroll
    for (int e = 0; e < 8; ++e) ones[e] = (short)0x3F80;   // bf16 1.0

    STAGE(0, 0);
    asm volatile("s_waitcnt vmcnt(0)" ::: "memory");
    __syncthreads();

    for (int kt = 0; kt < 32; ++kt) {
        const int cur = kt & 1;
        if (kt < 31) STAGE(kt + 1, cur ^ 1);   // prefetch next tile (in flight)

        // QK^T swapped: s[kj] holds S^T[k=kj*16+g4+r][q=wq0+rsel]
        f32x4 s[4];
#pragma unroll
        for (int kj = 0; kj < 4; ++kj) s[kj] = (f32x4){0.f, 0.f, 0.f, 0.f};
        __builtin_amdgcn_s_setprio(1);
#pragma unroll
        for (int ks = 0; ks < 2; ++ks) {
            bf16x8 ak[4];
            const int sl = ((ks * 4 + g) ^ r7) * 8;
#pragma unroll
            for (int kj = 0; kj < 4; ++kj)
                ak[kj] = *(const bf16x8*)(&Ks[cur][kj * 16 + rsel][sl]);
#pragma unroll
            for (int kj = 0; kj < 4; ++kj)
                s[kj] = mfma16(ak[kj], bq[ks], s[kj]);
        }
        __builtin_amdgcn_s_setprio(0);

        // P = exp2(s); pack to bf16; swizzled store into per-wave Ps
#pragma unroll
        for (int kj = 0; kj < 4; ++kj) {
            float p0 = exp2f(s[kj][0]);
            float p1 = exp2f(s[kj][1]);
            float p2 = exp2f(s[kj][2]);
            float p3 = exp2f(s[kj][3]);
            union { __hip_bfloat162 h2[2]; uint2 u; } pk;
            pk.h2[0] = __float22bfloat162_rn(make_float2(p0, p1));
            pk.h2[1] = __float22bfloat162_rn(make_float2(p2, p3));
            const int slot16 = (kj * 2 + (g >> 1)) ^ r7;
            *(uint2*)(&Ps[wid][rsel][slot16 * 8 + (g & 1) * 4]) = pk.u;
        }

        // PV + row-sum via ones (same-wave LDS dep; compiler inserts lgkmcnt)
        __builtin_amdgcn_s_setprio(1);
#pragma unroll
        for (int ks = 0; ks < 2; ++ks) {
            const int sl = ((ks * 4 + g) ^ r7) * 8;
            bf16x8 pa = *(const bf16x8*)(&Ps[wid][rsel][sl]);
            bf16x8 vb[4];
#pragma unroll
            for (int dj = 0; dj < 4; ++dj)
                vb[dj] = *(const bf16x8*)(&Vs[cur][dj * 16 + rsel][sl]);
#pragma unroll
            for (int dj = 0; dj < 4; ++dj)
                o[dj] = mfma16(pa, vb[dj], o[dj]);
            ol = mfma16(pa, ones, ol);         // l[q=g4+r] in ol[r], lane-local
        }
        __builtin_amdgcn_s_setprio(0);

        asm volatile("s_waitcnt vmcnt(0)" ::: "memory");  // next tile landed
        __syncthreads();
    }

    // epilogue: beta*softmax + alpha*V[q] - gamma/n * vsum
    const float alpha = *alpha_p, beta = *beta_p;
    const float gn = (*gamma_p) / 2048.0f;
    float linv[4];
#pragma unroll
    for (int r = 0; r < 4; ++r)
        linv[r] = beta / ol[r];
#pragma unroll
    for (int dj = 0; dj < 4; ++dj)
#pragma unroll
        for (int r = 0; r < 4; ++r) {
            int qrow = q0 + wq0 + g4 + r;
            int dv = dj * 16 + rsel;
            float ov = o[dj][r] * linv[r];
            float vdiag = bf2f(qkv[(size_t)(b * 2048 + qrow) * 3072 + 2048 + h * 64 + dv]);
            float vs = vsum[bh * 64 + dv];
            float res = ov + alpha * vdiag - gn * vs;
            AO[(size_t)(b * 2048 + qrow) * 1024 + h * 64 + dv] = f2bf(res);
        }
#undef STAGE
}

// ---------------------------------------------------------------------------
// GEMM2: out f32[4096][1024] = AO bf16 @ Wt2^T + bias
// ---------------------------------------------------------------------------
__global__ __launch_bounds__(256) void k_gemm2(
    const unsigned short* __restrict__ A, const unsigned short* __restrict__ B,
    const float* __restrict__ bias, float* __restrict__ Out)
{
    __shared__ unsigned short As[128 * 64];
    __shared__ unsigned short Bs[128 * 64];
    const int tid = threadIdx.x, lane = tid & 63, wid = tid >> 6;
    const int wr = (wid >> 1) * 64, wc = (wid & 1) * 64;
    const int row0 = blockIdx.y * 128, col0 = blockIdx.x * 128;
    const int rsel = lane & 15, kgr = (lane >> 4) * 8;
    const int lr = lane >> 3, lc = (lane & 7) * 8;

    f32x4 acc[4][4];
#pragma unroll
    for (int i = 0; i < 4; ++i)
#pragma unroll
        for (int j = 0; j < 4; ++j) acc[i][j] = (f32x4){0.f, 0.f, 0.f, 0.f};

    for (int k0 = 0; k0 < 1024; k0 += 64) {
        __syncthreads();
#pragma unroll
        for (int i = 0; i < 4; ++i) {
            int rb = wid * 32 + i * 8;
            gload_lds16(A + (size_t)(row0 + rb + lr) * 1024 + k0 + lc, As + rb * 64);
            gload_lds16(B + (size_t)(col0 + rb + lr) * 1024 + k0 + lc, Bs + rb * 64);
        }
        __syncthreads();
#pragma unroll
        for (int ks = 0; ks < 2; ++ks) {
            bf16x8 a[4], b[4];
            int ko = ks * 32 + kgr;
#pragma unroll
            for (int mi = 0; mi < 4; ++mi)
                a[mi] = *(const bf16x8*)(As + (wr + mi * 16 + rsel) * 64 + ko);
#pragma unroll
            for (int nj = 0; nj < 4; ++nj)
                b[nj] = *(const bf16x8*)(Bs + (wc + nj * 16 + rsel) * 64 + ko);
#pragma unroll
            for (int mi = 0; mi < 4; ++mi)
#pragma unroll
                for (int nj = 0; nj < 4; ++nj)
                    acc[mi][nj] = mfma16(a[mi], b[nj], acc[mi][nj]);
        }
    }
    const int rbase = row0 + wr + ((lane >> 4) << 2);
    const int cbase = col0 + wc + rsel;
#pragma unroll
    for (int mi = 0; mi < 4; ++mi)
#pragma unroll
        for (int nj = 0; nj < 4; ++nj) {
            int gc = cbase + nj * 16;
            float bv = bias[gc];
#pragma unroll
            for (int r = 0; r < 4; ++r)
                Out[(size_t)(rbase + mi * 16 + r) * 1024 + gc] = acc[mi][nj][r] + bv;
        }
}

// ---------------------------------------------------------------------------
extern "C" void kernel_launch(void* const* d_in, const int* in_sizes, int n_in,
                              void* d_out, int out_size, void* d_ws, size_t ws_size,
                              hipStream_t stream) {
    const float* x     = (const float*)d_in[0];
    const float* Wqkv  = (const float*)d_in[1];
    const float* Wout  = (const float*)d_in[2];
    const float* bout  = (const float*)d_in[3];
    const float* alpha = (const float*)d_in[4];
    const float* beta  = (const float*)d_in[5];
    const float* gamma = (const float*)d_in[6];
    float* out = (float*)d_out;

    char* ws = (char*)d_ws;
    unsigned short* Xb  = (unsigned short*)(ws);               // 8 MB (reused as AO)
    unsigned short* Wt1 = (unsigned short*)(ws + 8388608);     // 6 MB
    unsigned short* Wt2 = (unsigned short*)(ws + 14680064);    // 2 MB
    unsigned short* qkv = (unsigned short*)(ws + 16777216);    // 24 MB
    unsigned short* Vt  = (unsigned short*)(ws + 41943040);    // 8 MB
    float* vsum         = (float*)(ws + 50331648);             // 8 KB
    unsigned short* AO  = Xb;   // Xb dead after k_gemm1

    k_cvt<<<1024, 256, 0, stream>>>(x, Xb);
    k_wt<<<dim3(48, 16), 256, 0, stream>>>(Wqkv, Wt1, 3072);
    k_wt<<<dim3(16, 16), 256, 0, stream>>>(Wout, Wt2, 1024);
    k_gemm1<<<dim3(24, 32), 256, 0, stream>>>(Xb, Wt1, qkv);
    k_vt<<<dim3(32, 32), 256, 0, stream>>>(qkv, Vt);
    k_vsum<<<512, 256, 0, stream>>>(Vt, vsum);
    k_attn<<<1024, 256, 0, stream>>>(qkv, Vt, vsum, alpha, beta, gamma, AO);
    k_gemm2<<<dim3(8, 32), 256, 0, stream>>>(AO, Wt2, bout, out);
}